// Round 3
// baseline (1099.199 us; speedup 1.0000x reference)
//
#include <hip/hip_runtime.h>
#include <math.h>

#define BB   64
#define NIN  512
#define NH   512
#define TT   512

typedef _Float16 half2_t __attribute__((ext_vector_type(2)));
typedef _Float16 half8_t __attribute__((ext_vector_type(8)));
typedef float    f32x4  __attribute__((ext_vector_type(4)));

__device__ __forceinline__ unsigned pk16(float x, float y) {
    unsigned lo = (unsigned)__builtin_bit_cast(unsigned short, (_Float16)x);
    unsigned hi = (unsigned)__builtin_bit_cast(unsigned short, (_Float16)y);
    return lo | (hi << 16);
}

__device__ __forceinline__ float dot2u(unsigned w, unsigned a, float acc) {
    return __builtin_amdgcn_fdot2(__builtin_bit_cast(half2_t, w),
                                  __builtin_bit_cast(half2_t, a), acc, false);
}

__device__ __forceinline__ float tanh_fast(float x) {
    float ax = __builtin_fabsf(x);
    float e  = __builtin_amdgcn_exp2f(-2.885390082f * ax);   // exp(-2|x|)
    float r  = (1.0f - e) * __builtin_amdgcn_rcpf(1.0f + e);
    return __builtin_copysignf(r, x);
}

// ---------------------------------------------------------------------------
// K1 (MFMA): u[t][b][h] = sum_i X[b][i][t]*Wax[i][h] + bx[h] + ba[h].
// 128x128 tile (t x h), BK=32, 256 thr = 4 waves of 64x64. fp16 MFMA
// 16x16x32, f32 accumulate. (unchanged — verified)
// ---------------------------------------------------------------------------
__global__ __launch_bounds__(256) void inp_proj_mfma(
    const float* __restrict__ X, const float* __restrict__ Wax,
    const float* __restrict__ bx, const float* __restrict__ ba,
    float* __restrict__ out)
{
    __shared__ unsigned Xsp[16][132];   // [k-pair][t]  packed half2 (k0,k1)
    __shared__ unsigned Wsp[16][132];   // [k-pair][h]  packed half2

    const int b   = blockIdx.z;
    const int t0  = blockIdx.y * 128;
    const int h0  = blockIdx.x * 128;
    const int tid = threadIdx.x;
    const int lane = tid & 63;
    const int wid  = tid >> 6;
    const int wm   = wid >> 1;          // wave t-half  (0..1)
    const int wn   = wid & 1;           // wave h-half  (0..1)
    const int q    = lane >> 4;         // k-group 0..3 (k = 8q..8q+7)
    const int r16  = lane & 15;         // row/col within 16

    const int lr = tid >> 4;            // staging pair-row 0..15
    const int lc = (tid & 15) * 8;      // staging col (8 dwords/thread)

    const float* Xb = X + (size_t)b * NIN * TT;

    f32x4 acc[4][4] = {};               // [mt][nt], 4 f32 each

    for (int i0 = 0; i0 < NIN; i0 += 32) {
        const int k0 = i0 + 2 * lr, k1 = k0 + 1;
        float4 xa0 = *(const float4*)&Xb[(size_t)k0 * TT + t0 + lc];
        float4 xa1 = *(const float4*)&Xb[(size_t)k0 * TT + t0 + lc + 4];
        float4 xb0 = *(const float4*)&Xb[(size_t)k1 * TT + t0 + lc];
        float4 xb1 = *(const float4*)&Xb[(size_t)k1 * TT + t0 + lc + 4];
        float4 wa0 = *(const float4*)&Wax[(size_t)k0 * NH + h0 + lc];
        float4 wa1 = *(const float4*)&Wax[(size_t)k0 * NH + h0 + lc + 4];
        float4 wb0 = *(const float4*)&Wax[(size_t)k1 * NH + h0 + lc];
        float4 wb1 = *(const float4*)&Wax[(size_t)k1 * NH + h0 + lc + 4];

        uint4 xp0, xp1, wp0, wp1;
        xp0.x = pk16(xa0.x, xb0.x); xp0.y = pk16(xa0.y, xb0.y);
        xp0.z = pk16(xa0.z, xb0.z); xp0.w = pk16(xa0.w, xb0.w);
        xp1.x = pk16(xa1.x, xb1.x); xp1.y = pk16(xa1.y, xb1.y);
        xp1.z = pk16(xa1.z, xb1.z); xp1.w = pk16(xa1.w, xb1.w);
        wp0.x = pk16(wa0.x, wb0.x); wp0.y = pk16(wa0.y, wb0.y);
        wp0.z = pk16(wa0.z, wb0.z); wp0.w = pk16(wa0.w, wb0.w);
        wp1.x = pk16(wa1.x, wb1.x); wp1.y = pk16(wa1.y, wb1.y);
        wp1.z = pk16(wa1.z, wb1.z); wp1.w = pk16(wa1.w, wb1.w);

        __syncthreads();                // protect previous iter's readers
        *(uint4*)&Xsp[lr][lc]     = xp0;
        *(uint4*)&Xsp[lr][lc + 4] = xp1;
        *(uint4*)&Wsp[lr][lc]     = wp0;
        *(uint4*)&Wsp[lr][lc + 4] = wp1;
        __syncthreads();

        // fragment loads: pair p = 4q+j gives halves k = 8q+2j, 8q+2j+1
        uint4 af[4], bf[4];
#pragma unroll
        for (int mt = 0; mt < 4; ++mt) {
            const int tc = wm * 64 + mt * 16 + r16;
            af[mt].x = Xsp[4 * q + 0][tc];
            af[mt].y = Xsp[4 * q + 1][tc];
            af[mt].z = Xsp[4 * q + 2][tc];
            af[mt].w = Xsp[4 * q + 3][tc];
        }
#pragma unroll
        for (int nt = 0; nt < 4; ++nt) {
            const int hc = wn * 64 + nt * 16 + r16;
            bf[nt].x = Wsp[4 * q + 0][hc];
            bf[nt].y = Wsp[4 * q + 1][hc];
            bf[nt].z = Wsp[4 * q + 2][hc];
            bf[nt].w = Wsp[4 * q + 3][hc];
        }
#pragma unroll
        for (int mt = 0; mt < 4; ++mt)
#pragma unroll
            for (int nt = 0; nt < 4; ++nt)
                acc[mt][nt] = __builtin_amdgcn_mfma_f32_16x16x32_f16(
                    __builtin_bit_cast(half8_t, af[mt]),
                    __builtin_bit_cast(half8_t, bf[nt]),
                    acc[mt][nt], 0, 0, 0);
    }

    // epilogue: C/D layout col = lane&15, row = (lane>>4)*4 + reg
#pragma unroll
    for (int nt = 0; nt < 4; ++nt) {
        const int h = h0 + wn * 64 + nt * 16 + r16;
        const float bias = bx[h] + ba[h];
#pragma unroll
        for (int mt = 0; mt < 4; ++mt) {
            const int trow = t0 + wm * 64 + mt * 16 + q * 4;
#pragma unroll
            for (int rr = 0; rr < 4; ++rr) {
                out[(size_t)(trow + rr) * (BB * NH) + (size_t)b * NH + h] =
                    acc[mt][nt][rr] + bias;
            }
        }
    }
}

// ---------------------------------------------------------------------------
// K2 v7: 1024 threads, ONE barrier per step. Thread (kq=tid>>7, cidx=tid&127)
// computes 4-column partials over its k-eighth (NRP=26 pairs in VGPR/AGPR,
// NLP=6 pairs in LDS uint4 rows = 96 KB). Partials go to a DOUBLE-BUFFERED
// part[2][8][512] (32 KB). After the single barrier, EVERY lane reduces the
// two columns matching its next-step a-pair (h = kq*64+2*l32): 8x
// ds_read_b64 (2-way bank alias = free), tanh x2, pk16 -> a_loc stays in
// REGISTER (no a_lds round-trip, no barrier B). Even waves store to out.
// Double-buffered part makes the single barrier race-free: step t's readers
// of part[t&1] are protected from step t+2's writers by two intervening
// barriers; step t+1 writes the other buffer.
// ---------------------------------------------------------------------------
#define NRP 26        // register-resident pairs per column
#define NLP 6         // LDS-resident pairs per column (uint4 rows)

__device__ __forceinline__ unsigned bline(unsigned a, int l) {
    return (unsigned)__builtin_amdgcn_readlane((int)a, l);
}

__global__ __launch_bounds__(1024, 4) void rnn_scan_v7(
    const float* __restrict__ Waa, float* __restrict__ out)
{
    __shared__ uint4 wldsv[NLP][1024];       // 96 KB [pair][tid] = 4 cols
    __shared__ float part[2][8][512];        // 32 KB k-eighth partials, dbuf

    const int tid  = threadIdx.x;
    const int b    = blockIdx.x;
    const int cidx = tid & 127;
    const int kq   = tid >> 7;               // k-eighth 0..7
    const int h4   = cidx * 4;
    const int l32  = tid & 31;
    const int wv   = tid >> 6;

    // ---- preamble: 4 columns x 32 pairs; 26 -> VGPR, 6 -> LDS ----
    unsigned w0[NRP], w1[NRP], w2[NRP], w3[NRP];
#pragma unroll
    for (int j = 0; j < NRP; ++j) {
        const int k = kq * 64 + 2 * j;
        float4 r0 = *(const float4*)&Waa[(size_t)k       * NH + h4];
        float4 r1 = *(const float4*)&Waa[(size_t)(k + 1) * NH + h4];
        w0[j] = pk16(r0.x, r1.x);
        w1[j] = pk16(r0.y, r1.y);
        w2[j] = pk16(r0.z, r1.z);
        w3[j] = pk16(r0.w, r1.w);
    }
#pragma unroll
    for (int p = 0; p < NLP; ++p) {
        const int k = kq * 64 + 2 * (NRP + p);
        float4 r0 = *(const float4*)&Waa[(size_t)k       * NH + h4];
        float4 r1 = *(const float4*)&Waa[(size_t)(k + 1) * NH + h4];
        uint4 wvv;
        wvv.x = pk16(r0.x, r1.x);
        wvv.y = pk16(r0.y, r1.y);
        wvv.z = pk16(r0.z, r1.z);
        wvv.w = pk16(r0.w, r1.w);
        wldsv[p][tid] = wvv;
    }
    __syncthreads();

    // this lane's reduce columns = its next-step a-pair (kq*32 + l32)
    const int h2 = kq * 64 + 2 * l32;
    const float* ub = out + (size_t)b * NH + h2;
    float2 u_cur = *(const float2*)ub;
    unsigned a_loc = 0u;                     // a_0 = 0 (packed f16 pair)
    const bool do_store = ((wv & 1) == 0);

    for (int t = 0; t < TT; ++t) {
        const int tn = (t + 1 < TT) ? (t + 1) : (TT - 1);
        float2 u_next = *(const float2*)&ub[(size_t)tn * (BB * NH)]; // prefetch

        float acc0 = 0.f, acc1 = 0.f, acc2 = 0.f, acc3 = 0.f;
#pragma unroll
        for (int j = 0; j < NRP; j += 2) {
            unsigned ra = bline(a_loc, j);
            unsigned rb = bline(a_loc, j + 1);
            acc0 = dot2u(w0[j], ra, acc0);
            acc1 = dot2u(w1[j], ra, acc1);
            acc2 = dot2u(w2[j], ra, acc2);
            acc3 = dot2u(w3[j], ra, acc3);
            acc0 = dot2u(w0[j + 1], rb, acc0);
            acc1 = dot2u(w1[j + 1], rb, acc1);
            acc2 = dot2u(w2[j + 1], rb, acc2);
            acc3 = dot2u(w3[j + 1], rb, acc3);
        }
#pragma unroll
        for (int p = 0; p < NLP; ++p) {
            unsigned ra = bline(a_loc, NRP + p);
            uint4 v = wldsv[p][tid];
            acc0 = dot2u(v.x, ra, acc0);
            acc1 = dot2u(v.y, ra, acc1);
            acc2 = dot2u(v.z, ra, acc2);
            acc3 = dot2u(v.w, ra, acc3);
        }

        float4 pv; pv.x = acc0; pv.y = acc1; pv.z = acc2; pv.w = acc3;
        *(float4*)&part[t & 1][kq][h4] = pv;
        __builtin_amdgcn_s_waitcnt(0xC07F);   // lgkmcnt(0)
        __builtin_amdgcn_s_barrier();         // the ONLY barrier per step

        // every lane: reduce its two columns (redundant x2 across waves)
        const float* pc = &part[t & 1][0][h2];
        float2 s0 = *(const float2*)&pc[0 * 512];
        float2 s1 = *(const float2*)&pc[1 * 512];
        float2 s2 = *(const float2*)&pc[2 * 512];
        float2 s3 = *(const float2*)&pc[3 * 512];
        float2 s4 = *(const float2*)&pc[4 * 512];
        float2 s5 = *(const float2*)&pc[5 * 512];
        float2 s6 = *(const float2*)&pc[6 * 512];
        float2 s7 = *(const float2*)&pc[7 * 512];
        float x0 = u_cur.x + (((s0.x + s1.x) + (s2.x + s3.x)) +
                              ((s4.x + s5.x) + (s6.x + s7.x)));
        float x1 = u_cur.y + (((s0.y + s1.y) + (s2.y + s3.y)) +
                              ((s4.y + s5.y) + (s6.y + s7.y)));
        float an0 = tanh_fast(x0);
        float an1 = tanh_fast(x1);
        if (do_store) {
            float2 st; st.x = an0; st.y = an1;
            *(float2*)&out[(size_t)t * (BB * NH) + (size_t)b * NH + h2] = st;
        }
        a_loc = pk16(an0, an1);               // next-step a, in register
        u_cur = u_next;
    }
}

extern "C" void kernel_launch(void* const* d_in, const int* in_sizes, int n_in,
                              void* d_out, int out_size, void* d_ws, size_t ws_size,
                              hipStream_t stream) {
    const float* X   = (const float*)d_in[0];
    const float* Wax = (const float*)d_in[1];
    const float* Waa = (const float*)d_in[2];
    const float* bx  = (const float*)d_in[3];
    const float* ba  = (const float*)d_in[4];
    float* out = (float*)d_out;

    dim3 g1(NH / 128, TT / 128, BB);
    inp_proj_mfma<<<g1, 256, 0, stream>>>(X, Wax, bx, ba, out);
    rnn_scan_v7<<<BB, 1024, 0, stream>>>(Waa, out);
}

// Round 4
// 965.159 us; speedup vs baseline: 1.1389x; 1.1389x over previous
//
#include <hip/hip_runtime.h>
#include <math.h>

#define BB   64
#define NIN  512
#define NH   512
#define TT   512

typedef _Float16 half2_t __attribute__((ext_vector_type(2)));
typedef _Float16 half8_t __attribute__((ext_vector_type(8)));
typedef float    f32x4  __attribute__((ext_vector_type(4)));

__device__ __forceinline__ unsigned pk16(float x, float y) {
    unsigned lo = (unsigned)__builtin_bit_cast(unsigned short, (_Float16)x);
    unsigned hi = (unsigned)__builtin_bit_cast(unsigned short, (_Float16)y);
    return lo | (hi << 16);
}

__device__ __forceinline__ float dot2u(unsigned w, unsigned a, float acc) {
    return __builtin_amdgcn_fdot2(__builtin_bit_cast(half2_t, w),
                                  __builtin_bit_cast(half2_t, a), acc, false);
}

__device__ __forceinline__ float tanh_fast(float x) {
    float ax = __builtin_fabsf(x);
    float e  = __builtin_amdgcn_exp2f(-2.885390082f * ax);   // exp(-2|x|)
    float r  = (1.0f - e) * __builtin_amdgcn_rcpf(1.0f + e);
    return __builtin_copysignf(r, x);
}

// ---------------------------------------------------------------------------
// K0: pack X [b][i][t] f32 and Wax [i][h] f32 into half2-pair dwords:
//   Xp[(b*256 + i/2)*512 + t] = (f16(X[b][i][t]), f16(X[b][i+1][t]))
//   Wp[(i/2)*512 + h]         = (f16(Wax[i][h]), f16(Wax[i+1][h]))
// Pure-BW pass (~98 MB); removes all packing VALU from K1's hot loop.
// ---------------------------------------------------------------------------
#define NX4 (BB * (NIN / 2) * (TT / 4))      // 2,097,152 uint4 units for X
#define NW4 ((NIN / 2) * (NH / 4))           // 32,768 uint4 units for Wax

__global__ __launch_bounds__(256) void pack_f16(
    const float* __restrict__ X, const float* __restrict__ Wax,
    unsigned* __restrict__ Xp, unsigned* __restrict__ Wp)
{
    const int gid = blockIdx.x * 256 + threadIdx.x;
    if (gid < NX4) {
        const int t4 = gid & (TT / 4 - 1);        // 0..127
        const int pr = gid >> 7;                  // [b][j] pair-row
        const int j  = pr & (NIN / 2 - 1);
        const int b  = pr >> 8;
        float4 r0 = *(const float4*)&X[((size_t)b * NIN + 2 * j    ) * TT + t4 * 4];
        float4 r1 = *(const float4*)&X[((size_t)b * NIN + 2 * j + 1) * TT + t4 * 4];
        uint4 o;
        o.x = pk16(r0.x, r1.x); o.y = pk16(r0.y, r1.y);
        o.z = pk16(r0.z, r1.z); o.w = pk16(r0.w, r1.w);
        *(uint4*)&Xp[(size_t)pr * TT + t4 * 4] = o;
    } else {
        const int g = gid - NX4;
        if (g < NW4) {
            const int h4 = g & (NH / 4 - 1);
            const int j  = g >> 7;
            float4 r0 = *(const float4*)&Wax[((size_t)(2 * j    )) * NH + h4 * 4];
            float4 r1 = *(const float4*)&Wax[((size_t)(2 * j + 1)) * NH + h4 * 4];
            uint4 o;
            o.x = pk16(r0.x, r1.x); o.y = pk16(r0.y, r1.y);
            o.z = pk16(r0.z, r1.z); o.w = pk16(r0.w, r1.w);
            *(uint4*)&Wp[(size_t)j * NH + h4 * 4] = o;
        }
    }
}

// ---------------------------------------------------------------------------
// K1' (MFMA, packed inputs): u[t][b][h] = X-row dot Wax-col + bx + ba.
// Same 128x128 tile / BK=32 / 4 waves / 16x16x32 f16 MFMA as the verified
// round-2 kernel, but staging is 4x dwordx4 load + 4x ds_write_b128 —
// zero pk16 VALU in the hot loop, half the staging bytes. MFMA operand
// values and order are bit-identical to round 2.
// ---------------------------------------------------------------------------
__global__ __launch_bounds__(256) void inp_proj_mfma_pk(
    const unsigned* __restrict__ Xp, const unsigned* __restrict__ Wp,
    const float* __restrict__ bx, const float* __restrict__ ba,
    float* __restrict__ out)
{
    __shared__ unsigned Xsp[16][132];   // [k-pair][t]  packed half2 (k0,k1)
    __shared__ unsigned Wsp[16][132];   // [k-pair][h]  packed half2

    const int b   = blockIdx.z;
    const int t0  = blockIdx.y * 128;
    const int h0  = blockIdx.x * 128;
    const int tid = threadIdx.x;
    const int lane = tid & 63;
    const int wid  = tid >> 6;
    const int wm   = wid >> 1;          // wave t-half  (0..1)
    const int wn   = wid & 1;           // wave h-half  (0..1)
    const int q    = lane >> 4;         // k-group 0..3 (k = 8q..8q+7)
    const int r16  = lane & 15;         // row/col within 16

    const int lr = tid >> 4;            // staging pair-row 0..15
    const int lc = (tid & 15) * 8;      // staging col (8 dwords/thread)

    const unsigned* Xb = Xp + (size_t)b * (NIN / 2) * TT;

    f32x4 acc[4][4] = {};               // [mt][nt], 4 f32 each

    for (int p0 = 0; p0 < NIN / 2; p0 += 16) {
        const unsigned* Arow = &Xb[(size_t)(p0 + lr) * TT + t0 + lc];
        const unsigned* Brow = &Wp[(size_t)(p0 + lr) * NH + h0 + lc];
        uint4 xa = *(const uint4*)&Arow[0];
        uint4 xb = *(const uint4*)&Arow[4];
        uint4 wa = *(const uint4*)&Brow[0];
        uint4 wb = *(const uint4*)&Brow[4];

        __syncthreads();                // protect previous iter's readers
        *(uint4*)&Xsp[lr][lc]     = xa;
        *(uint4*)&Xsp[lr][lc + 4] = xb;
        *(uint4*)&Wsp[lr][lc]     = wa;
        *(uint4*)&Wsp[lr][lc + 4] = wb;
        __syncthreads();

        // fragment loads: pair p = 4q+j gives halves k = 8q+2j, 8q+2j+1
        uint4 af[4], bf[4];
#pragma unroll
        for (int mt = 0; mt < 4; ++mt) {
            const int tc = wm * 64 + mt * 16 + r16;
            af[mt].x = Xsp[4 * q + 0][tc];
            af[mt].y = Xsp[4 * q + 1][tc];
            af[mt].z = Xsp[4 * q + 2][tc];
            af[mt].w = Xsp[4 * q + 3][tc];
        }
#pragma unroll
        for (int nt = 0; nt < 4; ++nt) {
            const int hc = wn * 64 + nt * 16 + r16;
            bf[nt].x = Wsp[4 * q + 0][hc];
            bf[nt].y = Wsp[4 * q + 1][hc];
            bf[nt].z = Wsp[4 * q + 2][hc];
            bf[nt].w = Wsp[4 * q + 3][hc];
        }
#pragma unroll
        for (int mt = 0; mt < 4; ++mt)
#pragma unroll
            for (int nt = 0; nt < 4; ++nt)
                acc[mt][nt] = __builtin_amdgcn_mfma_f32_16x16x32_f16(
                    __builtin_bit_cast(half8_t, af[mt]),
                    __builtin_bit_cast(half8_t, bf[nt]),
                    acc[mt][nt], 0, 0, 0);
    }

    // epilogue: C/D layout col = lane&15, row = (lane>>4)*4 + reg
#pragma unroll
    for (int nt = 0; nt < 4; ++nt) {
        const int h = h0 + wn * 64 + nt * 16 + r16;
        const float bias = bx[h] + ba[h];
#pragma unroll
        for (int mt = 0; mt < 4; ++mt) {
            const int trow = t0 + wm * 64 + mt * 16 + q * 4;
#pragma unroll
            for (int rr = 0; rr < 4; ++rr) {
                out[(size_t)(trow + rr) * (BB * NH) + (size_t)b * NH + h] =
                    acc[mt][nt][rr] + bias;
            }
        }
    }
}

// ---------------------------------------------------------------------------
// K1 fallback (round-2 verified, f32 inputs) — used only if ws too small.
// ---------------------------------------------------------------------------
__global__ __launch_bounds__(256) void inp_proj_mfma(
    const float* __restrict__ X, const float* __restrict__ Wax,
    const float* __restrict__ bx, const float* __restrict__ ba,
    float* __restrict__ out)
{
    __shared__ unsigned Xsp[16][132];
    __shared__ unsigned Wsp[16][132];

    const int b   = blockIdx.z;
    const int t0  = blockIdx.y * 128;
    const int h0  = blockIdx.x * 128;
    const int tid = threadIdx.x;
    const int lane = tid & 63;
    const int wid  = tid >> 6;
    const int wm   = wid >> 1;
    const int wn   = wid & 1;
    const int q    = lane >> 4;
    const int r16  = lane & 15;

    const int lr = tid >> 4;
    const int lc = (tid & 15) * 8;

    const float* Xb = X + (size_t)b * NIN * TT;

    f32x4 acc[4][4] = {};

    for (int i0 = 0; i0 < NIN; i0 += 32) {
        const int k0 = i0 + 2 * lr, k1 = k0 + 1;
        float4 xa0 = *(const float4*)&Xb[(size_t)k0 * TT + t0 + lc];
        float4 xa1 = *(const float4*)&Xb[(size_t)k0 * TT + t0 + lc + 4];
        float4 xb0 = *(const float4*)&Xb[(size_t)k1 * TT + t0 + lc];
        float4 xb1 = *(const float4*)&Xb[(size_t)k1 * TT + t0 + lc + 4];
        float4 wa0 = *(const float4*)&Wax[(size_t)k0 * NH + h0 + lc];
        float4 wa1 = *(const float4*)&Wax[(size_t)k0 * NH + h0 + lc + 4];
        float4 wb0 = *(const float4*)&Wax[(size_t)k1 * NH + h0 + lc];
        float4 wb1 = *(const float4*)&Wax[(size_t)k1 * NH + h0 + lc + 4];

        uint4 xp0, xp1, wp0, wp1;
        xp0.x = pk16(xa0.x, xb0.x); xp0.y = pk16(xa0.y, xb0.y);
        xp0.z = pk16(xa0.z, xb0.z); xp0.w = pk16(xa0.w, xb0.w);
        xp1.x = pk16(xa1.x, xb1.x); xp1.y = pk16(xa1.y, xb1.y);
        xp1.z = pk16(xa1.z, xb1.z); xp1.w = pk16(xa1.w, xb1.w);
        wp0.x = pk16(wa0.x, wb0.x); wp0.y = pk16(wa0.y, wb0.y);
        wp0.z = pk16(wa0.z, wb0.z); wp0.w = pk16(wa0.w, wb0.w);
        wp1.x = pk16(wa1.x, wb1.x); wp1.y = pk16(wa1.y, wb1.y);
        wp1.z = pk16(wa1.z, wb1.z); wp1.w = pk16(wa1.w, wb1.w);

        __syncthreads();
        *(uint4*)&Xsp[lr][lc]     = xp0;
        *(uint4*)&Xsp[lr][lc + 4] = xp1;
        *(uint4*)&Wsp[lr][lc]     = wp0;
        *(uint4*)&Wsp[lr][lc + 4] = wp1;
        __syncthreads();

        uint4 af[4], bf[4];
#pragma unroll
        for (int mt = 0; mt < 4; ++mt) {
            const int tc = wm * 64 + mt * 16 + r16;
            af[mt].x = Xsp[4 * q + 0][tc];
            af[mt].y = Xsp[4 * q + 1][tc];
            af[mt].z = Xsp[4 * q + 2][tc];
            af[mt].w = Xsp[4 * q + 3][tc];
        }
#pragma unroll
        for (int nt = 0; nt < 4; ++nt) {
            const int hc = wn * 64 + nt * 16 + r16;
            bf[nt].x = Wsp[4 * q + 0][hc];
            bf[nt].y = Wsp[4 * q + 1][hc];
            bf[nt].z = Wsp[4 * q + 2][hc];
            bf[nt].w = Wsp[4 * q + 3][hc];
        }
#pragma unroll
        for (int mt = 0; mt < 4; ++mt)
#pragma unroll
            for (int nt = 0; nt < 4; ++nt)
                acc[mt][nt] = __builtin_amdgcn_mfma_f32_16x16x32_f16(
                    __builtin_bit_cast(half8_t, af[mt]),
                    __builtin_bit_cast(half8_t, bf[nt]),
                    acc[mt][nt], 0, 0, 0);
    }

#pragma unroll
    for (int nt = 0; nt < 4; ++nt) {
        const int h = h0 + wn * 64 + nt * 16 + r16;
        const float bias = bx[h] + ba[h];
#pragma unroll
        for (int mt = 0; mt < 4; ++mt) {
            const int trow = t0 + wm * 64 + mt * 16 + q * 4;
#pragma unroll
            for (int rr = 0; rr < 4; ++rr) {
                out[(size_t)(trow + rr) * (BB * NH) + (size_t)b * NH + h] =
                    acc[mt][nt][rr] + bias;
            }
        }
    }
}

// ---------------------------------------------------------------------------
// K2 v6 (round-2 verified, 833 µs): 1024 threads, one block per batch.
// Thread (kq=tid>>7, cidx=tid&127) owns 4 columns over its k-eighth
// (24 pairs VGPR/AGPR, 8 pairs LDS uint4 rows = 128 KB). a_t broadcast via
// v_readlane; 8 k-partials reduced via LDS by threads 0..511. Two raw
// s_barriers/step. (v7 single-barrier variant regressed — reverted.)
// ---------------------------------------------------------------------------
#define NRP 24        // register-resident pairs per column
#define NLP 8         // LDS-resident pairs per column (uint4 rows)
#define PSTRIDE 516

__device__ __forceinline__ unsigned bline(unsigned a, int l) {
    return (unsigned)__builtin_amdgcn_readlane((int)a, l);
}

__global__ __launch_bounds__(1024, 4) void rnn_scan_v6(
    const float* __restrict__ Waa, float* __restrict__ out)
{
    __shared__ uint4    wldsv[NLP][1024];    // 128 KB [pair][tid] = 4 cols
    __shared__ unsigned a_lds[2][256];       // packed half2 pairs, dbl-buffered
    __shared__ float    part[8][PSTRIDE];    // k-eighth partials, 16.5 KB

    const int tid  = threadIdx.x;
    const int b    = blockIdx.x;
    const int cidx = tid & 127;
    const int kq   = tid >> 7;               // k-eighth 0..7
    const int h4   = cidx * 4;
    const int l32  = tid & 31;

    // ---- preamble: 4 columns x 32 pairs; 24 -> VGPR, 8 -> LDS ----
    unsigned w0[NRP], w1[NRP], w2[NRP], w3[NRP];
#pragma unroll
    for (int j = 0; j < NRP; ++j) {
        const int k = kq * 64 + 2 * j;
        float4 r0 = *(const float4*)&Waa[(size_t)k       * NH + h4];
        float4 r1 = *(const float4*)&Waa[(size_t)(k + 1) * NH + h4];
        w0[j] = pk16(r0.x, r1.x);
        w1[j] = pk16(r0.y, r1.y);
        w2[j] = pk16(r0.z, r1.z);
        w3[j] = pk16(r0.w, r1.w);
    }
#pragma unroll
    for (int p = 0; p < NLP; ++p) {
        const int k = kq * 64 + 2 * (NRP + p);
        float4 r0 = *(const float4*)&Waa[(size_t)k       * NH + h4];
        float4 r1 = *(const float4*)&Waa[(size_t)(k + 1) * NH + h4];
        uint4 wv;
        wv.x = pk16(r0.x, r1.x);
        wv.y = pk16(r0.y, r1.y);
        wv.z = pk16(r0.z, r1.z);
        wv.w = pk16(r0.w, r1.w);
        wldsv[p][tid] = wv;
    }

    if (tid < 256) a_lds[0][tid] = 0u;       // a_0 = 0
    __syncthreads();

    const int  hc  = tid & 511;              // reduce-phase column
    const bool red = (tid < 512);            // wave-uniform
    float* ob = out + (size_t)b * NH + hc;   // this thread's output column
    float u_cur = red ? ob[0] : 0.0f;

    for (int t = 0; t < TT; ++t) {
        const int tn = (t + 1 < TT) ? (t + 1) : (TT - 1);
        float u_next = red ? ob[(size_t)tn * (BB * NH)] : 0.0f;   // prefetch

        // wave-local a: lane l (mod 32) holds pair kq*32+l of a_t
        unsigned a_loc = a_lds[t & 1][kq * 32 + l32];

        float acc0 = 0.f, acc1 = 0.f, acc2 = 0.f, acc3 = 0.f;
#pragma unroll
        for (int j = 0; j < NRP; j += 2) {
            unsigned ra = bline(a_loc, j);
            unsigned rb = bline(a_loc, j + 1);
            acc0 = dot2u(w0[j], ra, acc0);
            acc1 = dot2u(w1[j], ra, acc1);
            acc2 = dot2u(w2[j], ra, acc2);
            acc3 = dot2u(w3[j], ra, acc3);
            acc0 = dot2u(w0[j + 1], rb, acc0);
            acc1 = dot2u(w1[j + 1], rb, acc1);
            acc2 = dot2u(w2[j + 1], rb, acc2);
            acc3 = dot2u(w3[j + 1], rb, acc3);
        }
#pragma unroll
        for (int p = 0; p < NLP; ++p) {
            unsigned ra = bline(a_loc, NRP + p);
            uint4 v = wldsv[p][tid];
            acc0 = dot2u(v.x, ra, acc0);
            acc1 = dot2u(v.y, ra, acc1);
            acc2 = dot2u(v.z, ra, acc2);
            acc3 = dot2u(v.w, ra, acc3);
        }

        float4 pv; pv.x = acc0; pv.y = acc1; pv.z = acc2; pv.w = acc3;
        *(float4*)&part[kq][h4] = pv;
        __builtin_amdgcn_s_waitcnt(0xC07F);   // lgkmcnt(0)
        __builtin_amdgcn_s_barrier();         // barrier A (raw)

        if (red) {
            float x = u_cur +
                (((part[0][hc] + part[1][hc]) + (part[2][hc] + part[3][hc])) +
                 ((part[4][hc] + part[5][hc]) + (part[6][hc] + part[7][hc])));
            float an = tanh_fast(x);
            ob[(size_t)t * (BB * NH)] = an;   // fire-and-forget store
            ((unsigned short*)a_lds[(t + 1) & 1])[hc] =
                __builtin_bit_cast(unsigned short, (_Float16)an);
        }
        u_cur = u_next;
        __builtin_amdgcn_s_waitcnt(0xC07F);   // lgkmcnt(0)
        __builtin_amdgcn_s_barrier();         // barrier B (raw)
    }
}

extern "C" void kernel_launch(void* const* d_in, const int* in_sizes, int n_in,
                              void* d_out, int out_size, void* d_ws, size_t ws_size,
                              hipStream_t stream) {
    const float* X   = (const float*)d_in[0];
    const float* Wax = (const float*)d_in[1];
    const float* Waa = (const float*)d_in[2];
    const float* bx  = (const float*)d_in[3];
    const float* ba  = (const float*)d_in[4];
    float* out = (float*)d_out;

    const size_t xp_dw = (size_t)BB * (NIN / 2) * TT;     // 8,388,608 dwords
    const size_t wp_dw = (size_t)(NIN / 2) * NH;          // 131,072 dwords
    const size_t need  = (xp_dw + wp_dw) * sizeof(unsigned);

    if (ws_size >= need) {
        unsigned* Xp = (unsigned*)d_ws;
        unsigned* Wp = Xp + xp_dw;
        const int npack = (NX4 + NW4 + 255) / 256;        // 8320 blocks
        pack_f16<<<npack, 256, 0, stream>>>(X, Wax, Xp, Wp);
        dim3 g1(NH / 128, TT / 128, BB);
        inp_proj_mfma_pk<<<g1, 256, 0, stream>>>(Xp, Wp, bx, ba, out);
    } else {
        dim3 g1(NH / 128, TT / 128, BB);
        inp_proj_mfma<<<g1, 256, 0, stream>>>(X, Wax, bx, ba, out);
    }
    rnn_scan_v6<<<BB, 1024, 0, stream>>>(Waa, out);
}